// Round 1
// baseline (1783.403 us; speedup 1.0000x reference)
//
#include <hip/hip_runtime.h>
#include <cstdint>
#include <cstddef>

// ---------------------------------------------------------------------------
// GIN forward: h = conv(x; eps0, W1a,W2a) -> conv(h; eps1, W1b,W2b) -> MLP head
// SpMM via per-call CSR build (counting sort), GEMMs via fp32 row-per-lane
// scalar-W kernel (no fp32 MFMA on CDNA4).
// ---------------------------------------------------------------------------

__global__ __launch_bounds__(256) void k_zero(int* p, int n) {
    int i = blockIdx.x * 256 + threadIdx.x;
    if (i < n) p[i] = 0;
}

__global__ __launch_bounds__(256) void k_hist(const int* __restrict__ row,
                                              int* __restrict__ cnt, int E) {
    int e = blockIdx.x * 256 + threadIdx.x;
    if (e < E) atomicAdd(&cnt[row[e]], 1);
}

// block scans 1024 elements (256 thr x 4); writes per-element EXCLUSIVE scan
// (within block) to base, block total to part[b].
__global__ __launch_bounds__(256) void k_scan1(const int* __restrict__ cnt,
                                               int* __restrict__ base,
                                               int* __restrict__ part, int N) {
    __shared__ int sd[256];
    int t = threadIdx.x;
    int i0 = blockIdx.x * 1024 + t * 4;
    int v0 = (i0 + 0 < N) ? cnt[i0 + 0] : 0;
    int v1 = (i0 + 1 < N) ? cnt[i0 + 1] : 0;
    int v2 = (i0 + 2 < N) ? cnt[i0 + 2] : 0;
    int v3 = (i0 + 3 < N) ? cnt[i0 + 3] : 0;
    int ts = v0 + v1 + v2 + v3;
    sd[t] = ts;
    __syncthreads();
    for (int off = 1; off < 256; off <<= 1) {
        int x = (t >= off) ? sd[t - off] : 0;
        __syncthreads();
        sd[t] += x;
        __syncthreads();
    }
    int excl = sd[t] - ts;
    if (i0 + 0 < N) base[i0 + 0] = excl;
    if (i0 + 1 < N) base[i0 + 1] = excl + v0;
    if (i0 + 2 < N) base[i0 + 2] = excl + v0 + v1;
    if (i0 + 3 < N) base[i0 + 3] = excl + v0 + v1 + v2;
    if (t == 255) part[blockIdx.x] = sd[255];
}

// single block: exclusive scan of part[NB], NB <= 256
__global__ __launch_bounds__(256) void k_scan2(int* part, int NB) {
    __shared__ int sd[256];
    int t = threadIdx.x;
    int v = (t < NB) ? part[t] : 0;
    sd[t] = v;
    __syncthreads();
    for (int off = 1; off < 256; off <<= 1) {
        int x = (t >= off) ? sd[t - off] : 0;
        __syncthreads();
        sd[t] += x;
        __syncthreads();
    }
    if (t < NB) part[t] = sd[t] - v;
}

__global__ __launch_bounds__(256) void k_scan3(int* __restrict__ base,
                                               int* __restrict__ cursor,
                                               const int* __restrict__ part,
                                               int N, int E) {
    int i = blockIdx.x * 256 + threadIdx.x;
    if (i < N) {
        int b = base[i] + part[i >> 10];
        base[i] = b;
        cursor[i] = b;
    }
    if (i == 0) base[N] = E;
}

__global__ __launch_bounds__(256) void k_scatter(const int* __restrict__ row,
                                                 const int* __restrict__ col,
                                                 const float* __restrict__ vals,
                                                 int* __restrict__ cursor,
                                                 int* __restrict__ colv,
                                                 float* __restrict__ valv, int E) {
    int e = blockIdx.x * 256 + threadIdx.x;
    if (e < E) {
        int p = atomicAdd(&cursor[row[e]], 1);
        colv[p] = col[e];
        valv[p] = vals[e];
    }
}

// Wt[k*M + m] = W[m*K + k]
__global__ __launch_bounds__(256) void k_transpose(const float* __restrict__ W,
                                                   float* __restrict__ Wt,
                                                   int M, int K) {
    int idx = blockIdx.x * 256 + threadIdx.x;
    if (idx < M * K) {
        int m = idx / K, k = idx - m * K;
        Wt[k * M + m] = W[idx];
    }
}

// Wave-per-node CSR SpMM, fused eps-residual:
//   Y[i] = (1+eps)*X[i] + sum_{e in row i} val[e] * X[col[e]]
// d = VEC*64 floats per row; lane covers VEC consecutive floats.
template <int VEC>
__global__ __launch_bounds__(256) void k_spmm(const int* __restrict__ base,
                                              const int* __restrict__ colv,
                                              const float* __restrict__ valv,
                                              const float* __restrict__ X,
                                              float* __restrict__ Y,
                                              const float* __restrict__ epsp,
                                              int N) {
    using VT = float __attribute__((ext_vector_type(VEC)));
    const int D = VEC * 64;
    int node = blockIdx.x * 4 + __builtin_amdgcn_readfirstlane(threadIdx.x >> 6);
    if (node >= N) return;
    int lane = threadIdx.x & 63;
    float scale = 1.0f + epsp[0];

    const float* xs = X + (size_t)node * D + lane * VEC;
    VT acc = *(const VT*)xs;
    acc *= scale;

    int s = base[node];
    int e = base[node + 1];
    int i = s;
    for (; i + 1 < e; i += 2) {
        int c0 = colv[i];
        int c1 = colv[i + 1];
        float v0 = valv[i];
        float v1 = valv[i + 1];
        VT x0 = *(const VT*)(X + (size_t)c0 * D + lane * VEC);
        VT x1 = *(const VT*)(X + (size_t)c1 * D + lane * VEC);
        acc += x0 * v0;
        acc += x1 * v1;
    }
    if (i < e) {
        int c0 = colv[i];
        float v0 = valv[i];
        VT x0 = *(const VT*)(X + (size_t)c0 * D + lane * VEC);
        acc += x0 * v0;
    }
    *(VT*)(Y + (size_t)node * D + lane * VEC) = acc;
}

// C[n][m] = sum_k A[n][k] * Wt[k][m] + bias[m], optional ReLU.
// Block = 256 thr = 4 waves; block covers 64 rows (lane = row), wave wq covers
// cols [wq*M/4, (wq+1)*M/4). A staged in LDS stride-33 (2-way banks = free),
// W streamed via scalar loads (wave-uniform addresses). In-place safe if K==M
// (each block reads exactly the rows it writes; reads drain before stores).
template <int K, int M, bool RELU>
__global__ __launch_bounds__(256) void k_gemm(const float* __restrict__ A,
                                              const float* __restrict__ Wt,
                                              const float* __restrict__ bias,
                                              float* __restrict__ C, int N) {
    constexpr int MW = M / 4;
    __shared__ float As[64 * 33];
    const int t = threadIdx.x;
    const int lane = t & 63;
    const int wq = __builtin_amdgcn_readfirstlane(t >> 6);
    const int r0 = blockIdx.x * 64;

    float acc[MW];
#pragma unroll
    for (int j = 0; j < MW; ++j) acc[j] = 0.0f;

    const int srow = t >> 3;        // 0..31
    const int scol = (t & 7) << 2;  // 0,4,...,28

    for (int k0 = 0; k0 < K; k0 += 32) {
#pragma unroll
        for (int p = 0; p < 2; ++p) {
            int m = srow + p * 32;
            int gr = r0 + m;
            if (gr >= N) gr = N - 1;  // clamp (valid mem; garbage rows unused)
            const float4 v = *(const float4*)(A + (size_t)gr * K + k0 + scol);
            As[m * 33 + scol + 0] = v.x;
            As[m * 33 + scol + 1] = v.y;
            As[m * 33 + scol + 2] = v.z;
            As[m * 33 + scol + 3] = v.w;
        }
        __syncthreads();
#pragma unroll 1
        for (int k = 0; k < 32; ++k) {
            float a = As[lane * 33 + k];
            const float* wr = Wt + (size_t)(k0 + k) * M + wq * MW;
#pragma unroll
            for (int j = 0; j < MW; ++j) acc[j] = fmaf(a, wr[j], acc[j]);
        }
        __syncthreads();
    }

    int n = r0 + lane;
    if (n < N) {
        const float* bp = bias + wq * MW;
        float* cp = C + (size_t)n * M + wq * MW;
#pragma unroll
        for (int j = 0; j < MW; ++j) {
            float v = acc[j] + bp[j];
            if (RELU) v = v > 0.0f ? v : 0.0f;
            cp[j] = v;
        }
    }
}

extern "C" void kernel_launch(void* const* d_in, const int* in_sizes, int n_in,
                              void* d_out, int out_size, void* d_ws, size_t ws_size,
                              hipStream_t stream) {
    const float* x    = (const float*)d_in[0];
    const int*   row  = (const int*)d_in[1];
    const int*   col  = (const int*)d_in[2];
    const float* vals = (const float*)d_in[3];
    const float* eps0 = (const float*)d_in[4];
    const float* W1a  = (const float*)d_in[5];
    const float* b1a  = (const float*)d_in[6];
    const float* W2a  = (const float*)d_in[7];
    const float* b2a  = (const float*)d_in[8];
    const float* eps1 = (const float*)d_in[9];
    const float* W1b  = (const float*)d_in[10];
    const float* b1b  = (const float*)d_in[11];
    const float* W2b  = (const float*)d_in[12];
    const float* b2b  = (const float*)d_in[13];
    const float* Wf1  = (const float*)d_in[14];
    const float* bf1  = (const float*)d_in[15];
    const float* Wf2  = (const float*)d_in[16];
    const float* bf2  = (const float*)d_in[17];
    float* out = (float*)d_out;

    const int N = in_sizes[0] / 128;  // 100000
    const int E = in_sizes[1];        // 1600000

    char* w = (char*)d_ws;
    auto alloc = [&](size_t bytes) -> void* {
        void* p = (void*)w;
        w += (bytes + 255) & ~(size_t)255;
        return p;
    };
    float* B1     = (float*)alloc((size_t)N * 256 * 4);
    float* B2     = (float*)alloc((size_t)N * 256 * 4);
    int*   cnt    = (int*)alloc((size_t)N * 4);
    int*   basep  = (int*)alloc((size_t)(N + 1) * 4);
    int*   cursor = (int*)alloc((size_t)N * 4);
    int*   part   = (int*)alloc(1024);
    int*   colv   = (int*)alloc((size_t)E * 4);
    float* valv   = (float*)alloc((size_t)E * 4);
    float* Wt1a   = (float*)alloc(128 * 256 * 4);
    float* Wt2a   = (float*)alloc(256 * 256 * 4);
    float* Wt1b   = (float*)alloc(256 * 256 * 4);
    float* Wt2b   = (float*)alloc(256 * 256 * 4);
    float* Wtf1   = (float*)alloc(256 * 256 * 4);
    float* Wtf2   = (float*)alloc(256 * 64 * 4);

    // ---- CSR build ----
    k_zero<<<(N + 255) / 256, 256, 0, stream>>>(cnt, N);
    k_hist<<<(E + 255) / 256, 256, 0, stream>>>(row, cnt, E);
    int nb = (N + 1023) / 1024;  // 98
    k_scan1<<<nb, 256, 0, stream>>>(cnt, basep, part, N);
    k_scan2<<<1, 256, 0, stream>>>(part, nb);
    k_scan3<<<(N + 255) / 256, 256, 0, stream>>>(basep, cursor, part, N, E);
    k_scatter<<<(E + 255) / 256, 256, 0, stream>>>(row, col, vals, cursor, colv, valv, E);

    // ---- weight transposes (W[M][K] -> Wt[K][M]) ----
    k_transpose<<<(256 * 128 + 255) / 256, 256, 0, stream>>>(W1a, Wt1a, 256, 128);
    k_transpose<<<(256 * 256 + 255) / 256, 256, 0, stream>>>(W2a, Wt2a, 256, 256);
    k_transpose<<<(256 * 256 + 255) / 256, 256, 0, stream>>>(W1b, Wt1b, 256, 256);
    k_transpose<<<(256 * 256 + 255) / 256, 256, 0, stream>>>(W2b, Wt2b, 256, 256);
    k_transpose<<<(256 * 256 + 255) / 256, 256, 0, stream>>>(Wf1, Wtf1, 256, 256);
    k_transpose<<<(64 * 256 + 255) / 256, 256, 0, stream>>>(Wf2, Wtf2, 64, 256);

    const int gemm_grid = (N + 63) / 64;
    const int spmm_grid = (N + 3) / 4;

    // ---- conv A ----
    k_spmm<2><<<spmm_grid, 256, 0, stream>>>(basep, colv, valv, x, B1, eps0, N);   // B1[N,128]
    k_gemm<128, 256, true ><<<gemm_grid, 256, 0, stream>>>(B1, Wt1a, b1a, B2, N);  // B2[N,256]
    k_gemm<256, 256, false><<<gemm_grid, 256, 0, stream>>>(B2, Wt2a, b2a, B2, N);  // h1 in-place

    // ---- conv B ----
    k_spmm<4><<<spmm_grid, 256, 0, stream>>>(basep, colv, valv, B2, B1, eps1, N);  // B1[N,256]
    k_gemm<256, 256, true ><<<gemm_grid, 256, 0, stream>>>(B1, Wt1b, b1b, B1, N);  // in-place
    k_gemm<256, 256, false><<<gemm_grid, 256, 0, stream>>>(B1, Wt2b, b2b, B1, N);  // h2 in-place

    // ---- head ----
    k_gemm<256, 256, true ><<<gemm_grid, 256, 0, stream>>>(B1, Wtf1, bf1, B1, N);  // in-place
    k_gemm<256, 64,  false><<<gemm_grid, 256, 0, stream>>>(B1, Wtf2, bf2, out, N); // [N,64]
}

// Round 2
// 1277.396 us; speedup vs baseline: 1.3961x; 1.3961x over previous
//
#include <hip/hip_runtime.h>
#include <cstdint>
#include <cstddef>

// ---------------------------------------------------------------------------
// GIN forward: h = conv(x; eps0, W1a,W2a) -> conv(h; eps1, W1b,W2b) -> MLP head
// SpMM via per-call CSR build (counting sort).
// GEMMs via split-bf16 MFMA (3 x mfma_f32_16x16x32_bf16 per tile: hi*hi +
// hi*lo + lo*hi), fp32-level accuracy, activations stay fp32 in memory.
// ---------------------------------------------------------------------------

using bf8 = __attribute__((ext_vector_type(8))) short;   // 8 bf16 in 4 VGPRs
using f4  = __attribute__((ext_vector_type(4))) float;   // mfma acc

__device__ inline unsigned short f2bf(float f) {          // RNE f32 -> bf16 bits
    unsigned int u = __float_as_uint(f);
    return (unsigned short)((u + 0x7FFFu + ((u >> 16) & 1u)) >> 16);
}
__device__ inline float bf2f(unsigned short h) {
    return __uint_as_float(((unsigned int)h) << 16);
}

__global__ __launch_bounds__(256) void k_zero(int* p, int n) {
    int i = blockIdx.x * 256 + threadIdx.x;
    if (i < n) p[i] = 0;
}

__global__ __launch_bounds__(256) void k_hist(const int* __restrict__ row,
                                              int* __restrict__ cnt, int E) {
    int e = blockIdx.x * 256 + threadIdx.x;
    if (e < E) atomicAdd(&cnt[row[e]], 1);
}

// block scans 1024 elements (256 thr x 4); per-element EXCLUSIVE scan within
// block to base, block total to part[b].
__global__ __launch_bounds__(256) void k_scan1(const int* __restrict__ cnt,
                                               int* __restrict__ base,
                                               int* __restrict__ part, int N) {
    __shared__ int sd[256];
    int t = threadIdx.x;
    int i0 = blockIdx.x * 1024 + t * 4;
    int v0 = (i0 + 0 < N) ? cnt[i0 + 0] : 0;
    int v1 = (i0 + 1 < N) ? cnt[i0 + 1] : 0;
    int v2 = (i0 + 2 < N) ? cnt[i0 + 2] : 0;
    int v3 = (i0 + 3 < N) ? cnt[i0 + 3] : 0;
    int ts = v0 + v1 + v2 + v3;
    sd[t] = ts;
    __syncthreads();
    for (int off = 1; off < 256; off <<= 1) {
        int x = (t >= off) ? sd[t - off] : 0;
        __syncthreads();
        sd[t] += x;
        __syncthreads();
    }
    int excl = sd[t] - ts;
    if (i0 + 0 < N) base[i0 + 0] = excl;
    if (i0 + 1 < N) base[i0 + 1] = excl + v0;
    if (i0 + 2 < N) base[i0 + 2] = excl + v0 + v1;
    if (i0 + 3 < N) base[i0 + 3] = excl + v0 + v1 + v2;
    if (t == 255) part[blockIdx.x] = sd[255];
}

__global__ __launch_bounds__(256) void k_scan2(int* part, int NB) {
    __shared__ int sd[256];
    int t = threadIdx.x;
    int v = (t < NB) ? part[t] : 0;
    sd[t] = v;
    __syncthreads();
    for (int off = 1; off < 256; off <<= 1) {
        int x = (t >= off) ? sd[t - off] : 0;
        __syncthreads();
        sd[t] += x;
        __syncthreads();
    }
    if (t < NB) part[t] = sd[t] - v;
}

__global__ __launch_bounds__(256) void k_scan3(int* __restrict__ base,
                                               int* __restrict__ cursor,
                                               const int* __restrict__ part,
                                               int N, int E) {
    int i = blockIdx.x * 256 + threadIdx.x;
    if (i < N) {
        int b = base[i] + part[i >> 10];
        base[i] = b;
        cursor[i] = b;
    }
    if (i == 0) base[N] = E;
}

__global__ __launch_bounds__(256) void k_scatter(const int* __restrict__ row,
                                                 const int* __restrict__ col,
                                                 const float* __restrict__ vals,
                                                 int* __restrict__ cursor,
                                                 int* __restrict__ colv,
                                                 float* __restrict__ valv, int E) {
    int e = blockIdx.x * 256 + threadIdx.x;
    if (e < E) {
        int p = atomicAdd(&cursor[row[e]], 1);
        colv[p] = col[e];
        valv[p] = vals[e];
    }
}

// Wave-per-node CSR SpMM, fused eps-residual:
//   Y[i] = (1+eps)*X[i] + sum_{e in row i} val[e] * X[col[e]]
template <int VEC>
__global__ __launch_bounds__(256) void k_spmm(const int* __restrict__ base,
                                              const int* __restrict__ colv,
                                              const float* __restrict__ valv,
                                              const float* __restrict__ X,
                                              float* __restrict__ Y,
                                              const float* __restrict__ epsp,
                                              int N) {
    using VT = float __attribute__((ext_vector_type(VEC)));
    const int D = VEC * 64;
    int node = blockIdx.x * 4 + __builtin_amdgcn_readfirstlane(threadIdx.x >> 6);
    if (node >= N) return;
    int lane = threadIdx.x & 63;
    float scale = 1.0f + epsp[0];

    const float* xs = X + (size_t)node * D + lane * VEC;
    VT acc = *(const VT*)xs;
    acc *= scale;

    int s = base[node];
    int e = base[node + 1];
    int i = s;
    for (; i + 1 < e; i += 2) {
        int c0 = colv[i];
        int c1 = colv[i + 1];
        float v0 = valv[i];
        float v1 = valv[i + 1];
        VT x0 = *(const VT*)(X + (size_t)c0 * D + lane * VEC);
        VT x1 = *(const VT*)(X + (size_t)c1 * D + lane * VEC);
        acc += x0 * v0;
        acc += x1 * v1;
    }
    if (i < e) {
        int c0 = colv[i];
        float v0 = valv[i];
        VT x0 = *(const VT*)(X + (size_t)c0 * D + lane * VEC);
        acc += x0 * v0;
    }
    *(VT*)(Y + (size_t)node * D + lane * VEC) = acc;
}

// ---------------------------------------------------------------------------
// W prep: split W[M][K] fp32 into bf16 hi/lo arranged in exact B-fragment
// order for mfma_f32_16x16x32_bf16:
//   Wf[((c*(M/16)+ct)*64 + lane)*16 + {0..7}=hi, {8..15}=lo]
// where B[k][n]: n = ct*16 + (lane&15), k = c*32 + (lane>>4)*8 + j.
// ---------------------------------------------------------------------------
template <int K, int M>
__global__ __launch_bounds__(256) void k_wprep(const float* __restrict__ W,
                                               short* __restrict__ Wf) {
    int idx = blockIdx.x * 256 + threadIdx.x;   // one thread per (c,ct,lane,j)
    if (idx >= K * M) return;
    int group = idx >> 9;          // (c, ct)
    int r     = idx & 511;
    int lane  = r >> 3;
    int j     = r & 7;
    int c  = group / (M / 16);
    int ct = group - c * (M / 16);
    int n = ct * 16 + (lane & 15);
    int k = c * 32 + (lane >> 4) * 8 + j;
    float w = W[(size_t)n * K + k];
    unsigned short hi = f2bf(w);
    float res = w - bf2f(hi);
    unsigned short lo = f2bf(res);
    size_t base = (size_t)group * 1024 + (size_t)lane * 16;
    Wf[base + j]     = (short)hi;
    Wf[base + 8 + j] = (short)lo;
}

__device__ inline void split8(float4 a, float4 b, bf8& hi, bf8& lo) {
    float v[8] = {a.x, a.y, a.z, a.w, b.x, b.y, b.z, b.w};
#pragma unroll
    for (int i = 0; i < 8; ++i) {
        unsigned short h = f2bf(v[i]);
        float res = v[i] - bf2f(h);
        hi[i] = (short)h;
        lo[i] = (short)f2bf(res);
    }
}

// ---------------------------------------------------------------------------
// Split-bf16 MFMA GEMM: C[n][m] = A[n][:] . W[m][:] + bias[m]  (optional ReLU)
// Block = 256 thr = 4 waves, tile = 64 rows x M cols.
// Wave wq owns cols [wq*M/4, (wq+1)*M/4), all 64 rows (4 row-tiles of 16).
// A frags loaded straight from global fp32 (each element once per block),
// split to bf16 hi/lo in-register. W frags pre-split/pre-swizzled (k_wprep).
// 3 MFMAs per tile: Ah*Wh + Ah*Wl + Al*Wh  (error ~2^-16, fp32-grade).
// In-place (C==A, K==M) safe: all A reads drain before the pre-epilogue
// __syncthreads(); block writes only the rows it reads.
// ---------------------------------------------------------------------------
template <int K, int M, bool RELU>
__global__ __launch_bounds__(256) void k_gemm_mfma(const float* __restrict__ A,
                                                   const short* __restrict__ Wf,
                                                   const float* __restrict__ bias,
                                                   float* __restrict__ C, int N) {
    constexpr int NCT = M / 64;   // 16-wide col-tiles per wave (256->4, 64->1)
    constexpr int NCH = K / 32;   // k-chunks
    const int t    = threadIdx.x;
    const int lane = t & 63;
    const int wq   = t >> 6;
    const int r0   = blockIdx.x * 64;
    const int lm   = lane & 15;   // A row / B,C col within tile
    const int lq   = lane >> 4;   // quad
    const int c0   = wq * (M / 4);

    f4 acc[4][NCT];
#pragma unroll
    for (int rt = 0; rt < 4; ++rt)
#pragma unroll
        for (int ct = 0; ct < NCT; ++ct) acc[rt][ct] = (f4){0.f, 0.f, 0.f, 0.f};

#pragma unroll 2
    for (int c = 0; c < NCH; ++c) {
        const int kk = c * 32 + lq * 8;
        bf8 ah[4], al[4];
#pragma unroll
        for (int rt = 0; rt < 4; ++rt) {
            int gr = r0 + rt * 16 + lm;
            if (gr >= N) gr = N - 1;                 // clamp: valid mem, unused rows
            const float* ap = A + (size_t)gr * K + kk;
            float4 a01 = *(const float4*)(ap + 0);
            float4 a23 = *(const float4*)(ap + 4);
            split8(a01, a23, ah[rt], al[rt]);
        }
#pragma unroll
        for (int ct = 0; ct < NCT; ++ct) {
            const int ctg = wq * NCT + ct;
            const short* wp = Wf + ((size_t)(c * (M / 16) + ctg) * 64 + lane) * 16;
            bf8 wh = *(const bf8*)(wp);
            bf8 wl = *(const bf8*)(wp + 8);
#pragma unroll
            for (int rt = 0; rt < 4; ++rt) {
                acc[rt][ct] = __builtin_amdgcn_mfma_f32_16x16x32_bf16(ah[rt], wh, acc[rt][ct], 0, 0, 0);
                acc[rt][ct] = __builtin_amdgcn_mfma_f32_16x16x32_bf16(ah[rt], wl, acc[rt][ct], 0, 0, 0);
                acc[rt][ct] = __builtin_amdgcn_mfma_f32_16x16x32_bf16(al[rt], wh, acc[rt][ct], 0, 0, 0);
            }
        }
    }

    __syncthreads();   // drain all A reads before in-place writes

#pragma unroll
    for (int ct = 0; ct < NCT; ++ct) {
        const int col = c0 + ct * 16 + lm;
        const float bv = bias[col];
#pragma unroll
        for (int rt = 0; rt < 4; ++rt) {
#pragma unroll
            for (int reg = 0; reg < 4; ++reg) {
                int n = r0 + rt * 16 + lq * 4 + reg;
                if (n < N) {
                    float v = acc[rt][ct][reg] + bv;
                    if (RELU) v = v > 0.f ? v : 0.f;
                    C[(size_t)n * M + col] = v;
                }
            }
        }
    }
}

extern "C" void kernel_launch(void* const* d_in, const int* in_sizes, int n_in,
                              void* d_out, int out_size, void* d_ws, size_t ws_size,
                              hipStream_t stream) {
    const float* x    = (const float*)d_in[0];
    const int*   row  = (const int*)d_in[1];
    const int*   col  = (const int*)d_in[2];
    const float* vals = (const float*)d_in[3];
    const float* eps0 = (const float*)d_in[4];
    const float* W1a  = (const float*)d_in[5];
    const float* b1a  = (const float*)d_in[6];
    const float* W2a  = (const float*)d_in[7];
    const float* b2a  = (const float*)d_in[8];
    const float* eps1 = (const float*)d_in[9];
    const float* W1b  = (const float*)d_in[10];
    const float* b1b  = (const float*)d_in[11];
    const float* W2b  = (const float*)d_in[12];
    const float* b2b  = (const float*)d_in[13];
    const float* Wf1  = (const float*)d_in[14];
    const float* bf1  = (const float*)d_in[15];
    const float* Wf2  = (const float*)d_in[16];
    const float* bf2  = (const float*)d_in[17];
    float* out = (float*)d_out;

    const int N = in_sizes[0] / 128;  // 100000
    const int E = in_sizes[1];        // 1600000

    char* w = (char*)d_ws;
    auto alloc = [&](size_t bytes) -> void* {
        void* p = (void*)w;
        w += (bytes + 255) & ~(size_t)255;
        return p;
    };
    float* B1     = (float*)alloc((size_t)N * 256 * 4);
    float* B2     = (float*)alloc((size_t)N * 256 * 4);
    int*   cnt    = (int*)alloc((size_t)N * 4);
    int*   basep  = (int*)alloc((size_t)(N + 1) * 4);
    int*   cursor = (int*)alloc((size_t)N * 4);
    int*   part   = (int*)alloc(1024);
    int*   colv   = (int*)alloc((size_t)E * 4);
    float* valv   = (float*)alloc((size_t)E * 4);
    short* Wq1a   = (short*)alloc((size_t)128 * 256 * 2 * 2);
    short* Wq2a   = (short*)alloc((size_t)256 * 256 * 2 * 2);
    short* Wq1b   = (short*)alloc((size_t)256 * 256 * 2 * 2);
    short* Wq2b   = (short*)alloc((size_t)256 * 256 * 2 * 2);
    short* Wqf1   = (short*)alloc((size_t)256 * 256 * 2 * 2);
    short* Wqf2   = (short*)alloc((size_t)256 * 64 * 2 * 2);

    // ---- CSR build ----
    k_zero<<<(N + 255) / 256, 256, 0, stream>>>(cnt, N);
    k_hist<<<(E + 255) / 256, 256, 0, stream>>>(row, cnt, E);
    int nb = (N + 1023) / 1024;  // 98
    k_scan1<<<nb, 256, 0, stream>>>(cnt, basep, part, N);
    k_scan2<<<1, 256, 0, stream>>>(part, nb);
    k_scan3<<<(N + 255) / 256, 256, 0, stream>>>(basep, cursor, part, N, E);
    k_scatter<<<(E + 255) / 256, 256, 0, stream>>>(row, col, vals, cursor, colv, valv, E);

    // ---- weight split+swizzle into MFMA B-fragment layout ----
    k_wprep<128, 256><<<(128 * 256) / 256, 256, 0, stream>>>(W1a, Wq1a);
    k_wprep<256, 256><<<(256 * 256) / 256, 256, 0, stream>>>(W2a, Wq2a);
    k_wprep<256, 256><<<(256 * 256) / 256, 256, 0, stream>>>(W1b, Wq1b);
    k_wprep<256, 256><<<(256 * 256) / 256, 256, 0, stream>>>(W2b, Wq2b);
    k_wprep<256, 256><<<(256 * 256) / 256, 256, 0, stream>>>(Wf1, Wqf1);
    k_wprep<256, 64 ><<<(256 * 64 ) / 256, 256, 0, stream>>>(Wf2, Wqf2);

    const int gemm_grid = (N + 63) / 64;
    const int spmm_grid = (N + 3) / 4;

    // ---- conv A ----
    k_spmm<2><<<spmm_grid, 256, 0, stream>>>(basep, colv, valv, x, B1, eps0, N);        // B1[N,128]
    k_gemm_mfma<128, 256, true ><<<gemm_grid, 256, 0, stream>>>(B1, Wq1a, b1a, B2, N);  // B2[N,256]
    k_gemm_mfma<256, 256, false><<<gemm_grid, 256, 0, stream>>>(B2, Wq2a, b2a, B2, N);  // in-place

    // ---- conv B ----
    k_spmm<4><<<spmm_grid, 256, 0, stream>>>(basep, colv, valv, B2, B1, eps1, N);       // B1[N,256]
    k_gemm_mfma<256, 256, true ><<<gemm_grid, 256, 0, stream>>>(B1, Wq1b, b1b, B1, N);  // in-place
    k_gemm_mfma<256, 256, false><<<gemm_grid, 256, 0, stream>>>(B1, Wq2b, b2b, B1, N);  // in-place

    // ---- head ----
    k_gemm_mfma<256, 256, true ><<<gemm_grid, 256, 0, stream>>>(B1, Wqf1, bf1, B1, N);  // in-place
    k_gemm_mfma<256, 64,  false><<<gemm_grid, 256, 0, stream>>>(B1, Wqf2, bf2, out, N); // [N,64]
}

// Round 3
// 1199.336 us; speedup vs baseline: 1.4870x; 1.0651x over previous
//
#include <hip/hip_runtime.h>
#include <cstdint>
#include <cstddef>

// ---------------------------------------------------------------------------
// GIN forward: h = conv(x; eps0, W1a,W2a) -> conv(h; eps1, W1b,W2b) -> MLP head
// SpMM: per-call CSR build (counting sort) + shuffle-broadcast gather SpMM
//       with 8-deep gather pipelining (latency-bound -> more MLP).
// GEMM: split-bf16 MFMA (Ah*Wh + Ah*Wl + Al*Wh), fp32-grade accuracy.
//       Each Linear->ReLU->Linear pair fused into ONE kernel: hidden tile
//       round-trips through LDS (C-layout -> A-layout transform).
// ---------------------------------------------------------------------------

using bf8 = __attribute__((ext_vector_type(8))) short;   // 8 bf16 in 4 VGPRs
using f4  = __attribute__((ext_vector_type(4))) float;   // mfma acc

__device__ inline unsigned short f2bf(float f) {          // RNE f32 -> bf16 bits
    unsigned int u = __float_as_uint(f);
    return (unsigned short)((u + 0x7FFFu + ((u >> 16) & 1u)) >> 16);
}
__device__ inline float bf2f(unsigned short h) {
    return __uint_as_float(((unsigned int)h) << 16);
}

__global__ __launch_bounds__(256) void k_zero(int* p, int n) {
    int i = blockIdx.x * 256 + threadIdx.x;
    if (i < n) p[i] = 0;
}

__global__ __launch_bounds__(256) void k_hist(const int* __restrict__ row,
                                              int* __restrict__ cnt, int E) {
    int e = blockIdx.x * 256 + threadIdx.x;
    if (e < E) atomicAdd(&cnt[row[e]], 1);
}

// block scans 1024 elements (256 thr x 4); per-element EXCLUSIVE scan within
// block to base, block total to part[b].
__global__ __launch_bounds__(256) void k_scan1(const int* __restrict__ cnt,
                                               int* __restrict__ base,
                                               int* __restrict__ part, int N) {
    __shared__ int sd[256];
    int t = threadIdx.x;
    int i0 = blockIdx.x * 1024 + t * 4;
    int v0 = (i0 + 0 < N) ? cnt[i0 + 0] : 0;
    int v1 = (i0 + 1 < N) ? cnt[i0 + 1] : 0;
    int v2 = (i0 + 2 < N) ? cnt[i0 + 2] : 0;
    int v3 = (i0 + 3 < N) ? cnt[i0 + 3] : 0;
    int ts = v0 + v1 + v2 + v3;
    sd[t] = ts;
    __syncthreads();
    for (int off = 1; off < 256; off <<= 1) {
        int x = (t >= off) ? sd[t - off] : 0;
        __syncthreads();
        sd[t] += x;
        __syncthreads();
    }
    int excl = sd[t] - ts;
    if (i0 + 0 < N) base[i0 + 0] = excl;
    if (i0 + 1 < N) base[i0 + 1] = excl + v0;
    if (i0 + 2 < N) base[i0 + 2] = excl + v0 + v1;
    if (i0 + 3 < N) base[i0 + 3] = excl + v0 + v1 + v2;
    if (t == 255) part[blockIdx.x] = sd[255];
}

__global__ __launch_bounds__(256) void k_scan2(int* part, int NB) {
    __shared__ int sd[256];
    int t = threadIdx.x;
    int v = (t < NB) ? part[t] : 0;
    sd[t] = v;
    __syncthreads();
    for (int off = 1; off < 256; off <<= 1) {
        int x = (t >= off) ? sd[t - off] : 0;
        __syncthreads();
        sd[t] += x;
        __syncthreads();
    }
    if (t < NB) part[t] = sd[t] - v;
}

__global__ __launch_bounds__(256) void k_scan3(int* __restrict__ base,
                                               int* __restrict__ cursor,
                                               const int* __restrict__ part,
                                               int N, int E) {
    int i = blockIdx.x * 256 + threadIdx.x;
    if (i < N) {
        int b = base[i] + part[i >> 10];
        base[i] = b;
        cursor[i] = b;
    }
    if (i == 0) base[N] = E;
}

__global__ __launch_bounds__(256) void k_scatter(const int* __restrict__ row,
                                                 const int* __restrict__ col,
                                                 const float* __restrict__ vals,
                                                 int* __restrict__ cursor,
                                                 int* __restrict__ colv,
                                                 float* __restrict__ valv, int E) {
    int e = blockIdx.x * 256 + threadIdx.x;
    if (e < E) {
        int p = atomicAdd(&cursor[row[e]], 1);
        colv[p] = col[e];
        valv[p] = vals[e];
    }
}

// ---------------------------------------------------------------------------
// Wave-per-node CSR SpMM with shuffle-broadcast + 8-deep gather pipeline:
//   Y[i] = (1+eps)*X[i] + sum_{e in row i} val[e] * X[col[e]]
// One coalesced load grabs 64 (col,val) pairs; 8 independent row-gathers are
// issued back-to-back before accumulation (latency hiding). Tail lanes hold
// col=colv[s], val=0 -> harmless L2-hit gathers scaled by zero.
// ---------------------------------------------------------------------------
template <int VEC>
__global__ __launch_bounds__(256) void k_spmm(const int* __restrict__ base,
                                              const int* __restrict__ colv,
                                              const float* __restrict__ valv,
                                              const float* __restrict__ X,
                                              float* __restrict__ Y,
                                              const float* __restrict__ epsp,
                                              int N) {
    using VT = float __attribute__((ext_vector_type(VEC)));
    const int D = VEC * 64;
    int node = blockIdx.x * 4 + (threadIdx.x >> 6);
    if (node >= N) return;
    int lane = threadIdx.x & 63;
    float scale = 1.0f + epsp[0];
    const size_t off = (size_t)lane * VEC;

    VT acc = *(const VT*)(X + (size_t)node * D + off);
    acc *= scale;

    int s = base[node];
    int e = base[node + 1];
    for (int i0 = s; i0 < e; i0 += 64) {
        int rem = e - i0;                       // > 0
        int idx = i0 + (lane < rem ? lane : 0);
        int   ci = colv[idx];
        float vi = (lane < rem) ? valv[idx] : 0.0f;
        int lim = rem < 64 ? rem : 64;
        for (int j = 0; j < lim; j += 8) {
            int   cc[8];
            float vv[8];
#pragma unroll
            for (int u = 0; u < 8; ++u) {
                cc[u] = __shfl(ci, j + u);
                vv[u] = __shfl(vi, j + u);
            }
            VT xr[8];
#pragma unroll
            for (int u = 0; u < 8; ++u)
                xr[u] = *(const VT*)(X + (size_t)cc[u] * D + off);
#pragma unroll
            for (int u = 0; u < 8; ++u)
                acc += xr[u] * vv[u];
        }
    }
    *(VT*)(Y + (size_t)node * D + off) = acc;
}

// ---------------------------------------------------------------------------
// W prep: split W[M][K] fp32 into bf16 hi/lo in exact B-fragment order for
// mfma_f32_16x16x32_bf16:
//   Wf[((c*(M/16)+ct)*64 + lane)*16 + {0..7}=hi, {8..15}=lo]
// where B[k][n]: n = ct*16 + (lane&15), k = c*32 + (lane>>4)*8 + j.
// ---------------------------------------------------------------------------
__device__ inline void wprep_body(const float* __restrict__ W,
                                  short* __restrict__ Wf, int K, int M, int idx) {
    int group = idx >> 9;          // (c, ct)
    int r     = idx & 511;
    int lane  = r >> 3;
    int j     = r & 7;
    int c  = group / (M / 16);
    int ct = group - c * (M / 16);
    int n = ct * 16 + (lane & 15);
    int k = c * 32 + (lane >> 4) * 8 + j;
    float w = W[(size_t)n * K + k];
    unsigned short hi = f2bf(w);
    float res = w - bf2f(hi);
    unsigned short lo = f2bf(res);
    size_t b = (size_t)group * 1024 + (size_t)lane * 16;
    Wf[b + j]     = (short)hi;
    Wf[b + 8 + j] = (short)lo;
}

// one launch preps all six weights; block ranges hardcoded for this problem
__global__ __launch_bounds__(256) void k_wprep_all(
        const float* W1a, short* Q1a, const float* W2a, short* Q2a,
        const float* W1b, short* Q1b, const float* W2b, short* Q2b,
        const float* Wf1, short* Qf1, const float* Wf2, short* Qf2) {
    int b = blockIdx.x;
    const float* W; short* Q; int K, M, lb;
    if      (b < 128)  { W = W1a; Q = Q1a; K = 128; M = 256; lb = b; }
    else if (b < 384)  { W = W2a; Q = Q2a; K = 256; M = 256; lb = b - 128; }
    else if (b < 640)  { W = W1b; Q = Q1b; K = 256; M = 256; lb = b - 384; }
    else if (b < 896)  { W = W2b; Q = Q2b; K = 256; M = 256; lb = b - 640; }
    else if (b < 1152) { W = Wf1; Q = Qf1; K = 256; M = 256; lb = b - 896; }
    else               { W = Wf2; Q = Qf2; K = 256; M = 64;  lb = b - 1152; }
    wprep_body(W, Q, K, M, lb * 256 + threadIdx.x);
}

__device__ inline void split8(float4 a, float4 b, bf8& hi, bf8& lo) {
    float v[8] = {a.x, a.y, a.z, a.w, b.x, b.y, b.z, b.w};
#pragma unroll
    for (int i = 0; i < 8; ++i) {
        unsigned short h = f2bf(v[i]);
        float res = v[i] - bf2f(h);
        hi[i] = (short)h;
        lo[i] = (short)f2bf(res);
    }
}

// ---------------------------------------------------------------------------
// Fused MLP: C = relu(A @ W1^T + b1) @ W2^T + b2     (A: [N,K], hidden 256,
// out MO). Block = 256 thr = 4 waves, tile = 64 rows x all cols.
// GEMM1 accumulates the full 64x256 hidden tile (wave wq owns 64 cols); the
// ReLU'd tile goes to LDS (stride 260 words: 16B-aligned rows, <=2-way banks)
// performing the C-layout -> A-layout transform; GEMM2 reads A-frags from LDS.
// Split-bf16: 3 MFMAs per tile (Ah*Wh + Ah*Wl + Al*Wh), error ~2^-16.
// ---------------------------------------------------------------------------
template <int K, int MO>
__global__ __launch_bounds__(256) void k_mlp(const float* __restrict__ A,
                                             const short* __restrict__ Wq1,
                                             const float* __restrict__ b1,
                                             const short* __restrict__ Wq2,
                                             const float* __restrict__ b2,
                                             float* __restrict__ C, int N) {
    constexpr int MH   = 256;
    constexpr int NCT1 = MH / 64;   // 4 col-tiles per wave (GEMM1)
    constexpr int NCH1 = K / 32;
    constexpr int NCH2 = MH / 32;   // 8
    constexpr int NCT2 = MO / 64;   // 4 or 1
    constexpr int LS   = 260;       // LDS row stride (words): /4 -> b128 ok
    __shared__ float Hs[64 * LS];

    const int t    = threadIdx.x;
    const int lane = t & 63;
    const int wq   = t >> 6;
    const int r0   = blockIdx.x * 64;
    const int lm   = lane & 15;
    const int lq   = lane >> 4;

    // ---- GEMM1: A @ W1^T -> acc ----
    f4 acc[4][NCT1];
#pragma unroll
    for (int rt = 0; rt < 4; ++rt)
#pragma unroll
        for (int ct = 0; ct < NCT1; ++ct) acc[rt][ct] = (f4){0.f, 0.f, 0.f, 0.f};

#pragma unroll 2
    for (int c = 0; c < NCH1; ++c) {
        const int kk = c * 32 + lq * 8;
        bf8 ah[4], al[4];
#pragma unroll
        for (int rt = 0; rt < 4; ++rt) {
            int gr = r0 + rt * 16 + lm;
            if (gr >= N) gr = N - 1;             // clamp: valid mem, rows unused
            const float* ap = A + (size_t)gr * K + kk;
            float4 a01 = *(const float4*)(ap + 0);
            float4 a23 = *(const float4*)(ap + 4);
            split8(a01, a23, ah[rt], al[rt]);
        }
#pragma unroll
        for (int ct = 0; ct < NCT1; ++ct) {
            const int ctg = wq * NCT1 + ct;
            const short* wp = Wq1 + ((size_t)(c * (MH / 16) + ctg) * 64 + lane) * 16;
            bf8 wh = *(const bf8*)(wp);
            bf8 wl = *(const bf8*)(wp + 8);
#pragma unroll
            for (int rt = 0; rt < 4; ++rt) {
                acc[rt][ct] = __builtin_amdgcn_mfma_f32_16x16x32_bf16(ah[rt], wh, acc[rt][ct], 0, 0, 0);
                acc[rt][ct] = __builtin_amdgcn_mfma_f32_16x16x32_bf16(ah[rt], wl, acc[rt][ct], 0, 0, 0);
                acc[rt][ct] = __builtin_amdgcn_mfma_f32_16x16x32_bf16(al[rt], wh, acc[rt][ct], 0, 0, 0);
            }
        }
    }

    // ---- H = relu(acc + b1) -> LDS (C-layout write, 2-way banks = free) ----
#pragma unroll
    for (int ct = 0; ct < NCT1; ++ct) {
        const int col = wq * 64 + ct * 16 + lm;
        const float bv = b1[col];
#pragma unroll
        for (int rt = 0; rt < 4; ++rt) {
#pragma unroll
            for (int reg = 0; reg < 4; ++reg) {
                int rrow = rt * 16 + lq * 4 + reg;
                float v = acc[rt][ct][reg] + bv;
                v = v > 0.f ? v : 0.f;
                Hs[rrow * LS + col] = v;
            }
        }
    }
    __syncthreads();

    // ---- GEMM2: H @ W2^T + b2 -> C ----
    f4 acc2[4][NCT2];
#pragma unroll
    for (int rt = 0; rt < 4; ++rt)
#pragma unroll
        for (int ct = 0; ct < NCT2; ++ct) acc2[rt][ct] = (f4){0.f, 0.f, 0.f, 0.f};

#pragma unroll 2
    for (int c = 0; c < NCH2; ++c) {
        const int kk = c * 32 + lq * 8;
        bf8 ah[4], al[4];
#pragma unroll
        for (int rt = 0; rt < 4; ++rt) {
            const float* hp = &Hs[(rt * 16 + lm) * LS + kk];
            float4 a01 = *(const float4*)(hp + 0);
            float4 a23 = *(const float4*)(hp + 4);
            split8(a01, a23, ah[rt], al[rt]);
        }
#pragma unroll
        for (int ct = 0; ct < NCT2; ++ct) {
            const int ctg = wq * NCT2 + ct;
            const short* wp = Wq2 + ((size_t)(c * (MO / 16) + ctg) * 64 + lane) * 16;
            bf8 wh = *(const bf8*)(wp);
            bf8 wl = *(const bf8*)(wp + 8);
#pragma unroll
            for (int rt = 0; rt < 4; ++rt) {
                acc2[rt][ct] = __builtin_amdgcn_mfma_f32_16x16x32_bf16(ah[rt], wh, acc2[rt][ct], 0, 0, 0);
                acc2[rt][ct] = __builtin_amdgcn_mfma_f32_16x16x32_bf16(ah[rt], wl, acc2[rt][ct], 0, 0, 0);
                acc2[rt][ct] = __builtin_amdgcn_mfma_f32_16x16x32_bf16(al[rt], wh, acc2[rt][ct], 0, 0, 0);
            }
        }
    }

#pragma unroll
    for (int ct = 0; ct < NCT2; ++ct) {
        const int col = wq * (MO / 4) + ct * 16 + lm;
        const float bv = b2[col];
#pragma unroll
        for (int rt = 0; rt < 4; ++rt) {
#pragma unroll
            for (int reg = 0; reg < 4; ++reg) {
                int n = r0 + rt * 16 + lq * 4 + reg;
                if (n < N) C[(size_t)n * MO + col] = acc2[rt][ct][reg] + bv;
            }
        }
    }
}

extern "C" void kernel_launch(void* const* d_in, const int* in_sizes, int n_in,
                              void* d_out, int out_size, void* d_ws, size_t ws_size,
                              hipStream_t stream) {
    const float* x    = (const float*)d_in[0];
    const int*   row  = (const int*)d_in[1];
    const int*   col  = (const int*)d_in[2];
    const float* vals = (const float*)d_in[3];
    const float* eps0 = (const float*)d_in[4];
    const float* W1a  = (const float*)d_in[5];
    const float* b1a  = (const float*)d_in[6];
    const float* W2a  = (const float*)d_in[7];
    const float* b2a  = (const float*)d_in[8];
    const float* eps1 = (const float*)d_in[9];
    const float* W1b  = (const float*)d_in[10];
    const float* b1b  = (const float*)d_in[11];
    const float* W2b  = (const float*)d_in[12];
    const float* b2b  = (const float*)d_in[13];
    const float* Wf1  = (const float*)d_in[14];
    const float* bf1  = (const float*)d_in[15];
    const float* Wf2  = (const float*)d_in[16];
    const float* bf2  = (const float*)d_in[17];
    float* out = (float*)d_out;

    const int N = in_sizes[0] / 128;  // 100000
    const int E = in_sizes[1];        // 1600000

    char* w = (char*)d_ws;
    auto alloc = [&](size_t bytes) -> void* {
        void* p = (void*)w;
        w += (bytes + 255) & ~(size_t)255;
        return p;
    };
    float* B1     = (float*)alloc((size_t)N * 256 * 4);
    float* B2     = (float*)alloc((size_t)N * 256 * 4);
    int*   cnt    = (int*)alloc((size_t)N * 4);
    int*   basep  = (int*)alloc((size_t)(N + 1) * 4);
    int*   cursor = (int*)alloc((size_t)N * 4);
    int*   part   = (int*)alloc(1024);
    int*   colv   = (int*)alloc((size_t)E * 4);
    float* valv   = (float*)alloc((size_t)E * 4);
    short* Wq1a   = (short*)alloc((size_t)128 * 256 * 2 * 2);
    short* Wq2a   = (short*)alloc((size_t)256 * 256 * 2 * 2);
    short* Wq1b   = (short*)alloc((size_t)256 * 256 * 2 * 2);
    short* Wq2b   = (short*)alloc((size_t)256 * 256 * 2 * 2);
    short* Wqf1   = (short*)alloc((size_t)256 * 256 * 2 * 2);
    short* Wqf2   = (short*)alloc((size_t)256 * 64 * 2 * 2);

    // ---- CSR build ----
    k_zero<<<(N + 255) / 256, 256, 0, stream>>>(cnt, N);
    k_hist<<<(E + 255) / 256, 256, 0, stream>>>(row, cnt, E);
    int nb = (N + 1023) / 1024;  // 98
    k_scan1<<<nb, 256, 0, stream>>>(cnt, basep, part, N);
    k_scan2<<<1, 256, 0, stream>>>(part, nb);
    k_scan3<<<(N + 255) / 256, 256, 0, stream>>>(basep, cursor, part, N, E);
    k_scatter<<<(E + 255) / 256, 256, 0, stream>>>(row, col, vals, cursor, colv, valv, E);

    // ---- weight split+swizzle into MFMA B-fragment layout (one launch) ----
    k_wprep_all<<<1216, 256, 0, stream>>>(W1a, Wq1a, W2a, Wq2a, W1b, Wq1b,
                                          W2b, Wq2b, Wf1, Wqf1, Wf2, Wqf2);

    const int gemm_grid = (N + 63) / 64;
    const int spmm_grid = (N + 3) / 4;

    // ---- conv A ----
    k_spmm<2><<<spmm_grid, 256, 0, stream>>>(basep, colv, valv, x, B1, eps0, N);      // B1[N,128]
    k_mlp<128, 256><<<gemm_grid, 256, 0, stream>>>(B1, Wq1a, b1a, Wq2a, b2a, B2, N);  // B2[N,256]

    // ---- conv B ----
    k_spmm<4><<<spmm_grid, 256, 0, stream>>>(basep, colv, valv, B2, B1, eps1, N);     // B1[N,256]
    k_mlp<256, 256><<<gemm_grid, 256, 0, stream>>>(B1, Wq1b, b1b, Wq2b, b2b, B2, N);  // B2[N,256]

    // ---- head ----
    k_mlp<256, 64><<<gemm_grid, 256, 0, stream>>>(B2, Wqf1, bf1, Wqf2, bf2, out, N);  // [N,64]
}

// Round 4
// 919.645 us; speedup vs baseline: 1.9392x; 1.3041x over previous
//
#include <hip/hip_runtime.h>
#include <cstdint>
#include <cstddef>

// ---------------------------------------------------------------------------
// GIN forward: h = conv(x; eps0, W1a,W2a) -> conv(h; eps1, W1b,W2b) -> MLP head
// SpMM: per-call CSR build (counting sort, int2 edges) + bf16 multi-edge
//       gather SpMM (2 or 4 edges per 16B/lane gather instr), fp32 accumulate.
// GEMM: split-bf16 MFMA MLP pairs fused through LDS; head reads bf16 A
//       directly (2 MFMAs/tile). Activations between stages stored bf16 where
//       they only feed gathers / bf16-A GEMMs; spmm outputs stay fp32.
// ---------------------------------------------------------------------------

using bf8 = __attribute__((ext_vector_type(8))) short;   // 8 bf16 in 4 VGPRs
using us8 = __attribute__((ext_vector_type(8))) unsigned short;
using f4  = __attribute__((ext_vector_type(4))) float;   // mfma acc

__device__ inline unsigned short f2bf(float f) {          // RNE f32 -> bf16 bits
    unsigned int u = __float_as_uint(f);
    return (unsigned short)((u + 0x7FFFu + ((u >> 16) & 1u)) >> 16);
}
__device__ inline float bf2f(unsigned short h) {
    return __uint_as_float(((unsigned int)h) << 16);
}

__global__ __launch_bounds__(256) void k_zero(int* p, int n) {
    int i = blockIdx.x * 256 + threadIdx.x;
    if (i < n) p[i] = 0;
}

__global__ __launch_bounds__(256) void k_hist(const int* __restrict__ row,
                                              int* __restrict__ cnt, int E) {
    int e = blockIdx.x * 256 + threadIdx.x;
    if (e < E) atomicAdd(&cnt[row[e]], 1);
}

// block scans 1024 elements (256 thr x 4); per-element EXCLUSIVE scan within
// block to base, block total to part[b].
__global__ __launch_bounds__(256) void k_scan1(const int* __restrict__ cnt,
                                               int* __restrict__ base,
                                               int* __restrict__ part, int N) {
    __shared__ int sd[256];
    int t = threadIdx.x;
    int i0 = blockIdx.x * 1024 + t * 4;
    int v0 = (i0 + 0 < N) ? cnt[i0 + 0] : 0;
    int v1 = (i0 + 1 < N) ? cnt[i0 + 1] : 0;
    int v2 = (i0 + 2 < N) ? cnt[i0 + 2] : 0;
    int v3 = (i0 + 3 < N) ? cnt[i0 + 3] : 0;
    int ts = v0 + v1 + v2 + v3;
    sd[t] = ts;
    __syncthreads();
    for (int off = 1; off < 256; off <<= 1) {
        int x = (t >= off) ? sd[t - off] : 0;
        __syncthreads();
        sd[t] += x;
        __syncthreads();
    }
    int excl = sd[t] - ts;
    if (i0 + 0 < N) base[i0 + 0] = excl;
    if (i0 + 1 < N) base[i0 + 1] = excl + v0;
    if (i0 + 2 < N) base[i0 + 2] = excl + v0 + v1;
    if (i0 + 3 < N) base[i0 + 3] = excl + v0 + v1 + v2;
    if (t == 255) part[blockIdx.x] = sd[255];
}

__global__ __launch_bounds__(256) void k_scan2(int* part, int NB) {
    __shared__ int sd[256];
    int t = threadIdx.x;
    int v = (t < NB) ? part[t] : 0;
    sd[t] = v;
    __syncthreads();
    for (int off = 1; off < 256; off <<= 1) {
        int x = (t >= off) ? sd[t - off] : 0;
        __syncthreads();
        sd[t] += x;
        __syncthreads();
    }
    if (t < NB) part[t] = sd[t] - v;
}

__global__ __launch_bounds__(256) void k_scan3(int* __restrict__ base,
                                               int* __restrict__ cursor,
                                               const int* __restrict__ part,
                                               int N, int E) {
    int i = blockIdx.x * 256 + threadIdx.x;
    if (i < N) {
        int b = base[i] + part[i >> 10];
        base[i] = b;
        cursor[i] = b;
    }
    if (i == 0) base[N] = E;
}

__global__ __launch_bounds__(256) void k_scatter(const int* __restrict__ row,
                                                 const int* __restrict__ col,
                                                 const float* __restrict__ vals,
                                                 int* __restrict__ cursor,
                                                 int2* __restrict__ edges, int E) {
    int e = blockIdx.x * 256 + threadIdx.x;
    if (e < E) {
        int p = atomicAdd(&cursor[row[e]], 1);
        edges[p] = make_int2(col[e], __float_as_int(vals[e]));
    }
}

// fp32 -> bf16 cast, 4 elems/thread (n divisible by 4)
__global__ __launch_bounds__(256) void k_cvt(const float* __restrict__ x,
                                             unsigned short* __restrict__ xb, int n) {
    int i = (blockIdx.x * 256 + threadIdx.x) * 4;
    if (i < n) {
        float4 v = *(const float4*)(x + i);
        ushort4 o = {f2bf(v.x), f2bf(v.y), f2bf(v.z), f2bf(v.w)};
        *(ushort4*)(xb + i) = o;
    }
}

// ---------------------------------------------------------------------------
// Wave-per-node CSR SpMM on bf16 rows, fp32 accumulate, fused eps-residual:
//   Y[i] = (1+eps)*Xb[i] + sum_e val[e] * Xb[col[e]]
// Row = D bf16 (2*D bytes). L = D/8 lanes cover a row at 16B/lane; R = 64/L
// edges are gathered per instruction (lane partition). Butterfly-shfl reduce
// across edge-parts at the end; part 0 adds the self term and stores fp32 Y.
// ---------------------------------------------------------------------------
template <int D>
__global__ __launch_bounds__(256) void k_spmm_bf(const int* __restrict__ base,
                                                 const int2* __restrict__ edges,
                                                 const unsigned short* __restrict__ Xb,
                                                 float* __restrict__ Y,
                                                 const float* __restrict__ epsp,
                                                 int N) {
    constexpr int L = D / 8;    // lanes per row (16 or 32)
    constexpr int R = 64 / L;   // edges per gather instr (4 or 2)
    constexpr int U = 8 / R;    // instrs per inner iter -> 8 edges/iter
    int node = blockIdx.x * 4 + (threadIdx.x >> 6);
    if (node >= N) return;
    const int lane = threadIdx.x & 63;
    const int sub  = lane % L;   // 8-col group within row
    const int part = lane / L;   // which edge of the group
    const float scale = 1.0f + epsp[0];

    float acc[8];
#pragma unroll
    for (int k = 0; k < 8; ++k) acc[k] = 0.0f;

    const int s = base[node];
    const int e = base[node + 1];
    for (int i0 = s; i0 < e; i0 += 64) {
        int rem = e - i0;
        int idx = i0 + (lane < rem ? lane : 0);
        int2 ed = edges[idx];
        int   ci = ed.x;
        float vi = (lane < rem) ? __int_as_float(ed.y) : 0.0f;
        int lim = rem < 64 ? rem : 64;
        for (int j = 0; j < lim; j += 8) {
            int cc[U]; float vv[U];
#pragma unroll
            for (int u = 0; u < U; ++u) {
                int sl = j + u * R + part;      // <= 63 always
                cc[u] = __shfl(ci, sl);
                vv[u] = __shfl(vi, sl);
            }
            us8 g[U];
#pragma unroll
            for (int u = 0; u < U; ++u)
                g[u] = *(const us8*)(Xb + (size_t)cc[u] * D + sub * 8);
#pragma unroll
            for (int u = 0; u < U; ++u)
#pragma unroll
                for (int k = 0; k < 8; ++k)
                    acc[k] = fmaf(bf2f(g[u][k]), vv[u], acc[k]);
        }
    }

    // butterfly-reduce across edge parts (lanes L, 2L, ... apart)
#pragma unroll
    for (int st = L; st < 64; st <<= 1)
#pragma unroll
        for (int k = 0; k < 8; ++k)
            acc[k] += __shfl_xor(acc[k], st);

    if (part == 0) {
        us8 xs = *(const us8*)(Xb + (size_t)node * D + sub * 8);
        float o[8];
#pragma unroll
        for (int k = 0; k < 8; ++k) o[k] = acc[k] + scale * bf2f(xs[k]);
        float* yp = Y + (size_t)node * D + sub * 8;
        *(float4*)(yp + 0) = make_float4(o[0], o[1], o[2], o[3]);
        *(float4*)(yp + 4) = make_float4(o[4], o[5], o[6], o[7]);
    }
}

// ---------------------------------------------------------------------------
// W prep: split W[M][K] fp32 into bf16 hi/lo in exact B-fragment order for
// mfma_f32_16x16x32_bf16:
//   Wf[((c*(M/16)+ct)*64 + lane)*16 + {0..7}=hi, {8..15}=lo]
// where B[k][n]: n = ct*16 + (lane&15), k = c*32 + (lane>>4)*8 + j.
// ---------------------------------------------------------------------------
__device__ inline void wprep_body(const float* __restrict__ W,
                                  short* __restrict__ Wf, int K, int M, int idx) {
    int group = idx >> 9;          // (c, ct)
    int r     = idx & 511;
    int lane  = r >> 3;
    int j     = r & 7;
    int c  = group / (M / 16);
    int ct = group - c * (M / 16);
    int n = ct * 16 + (lane & 15);
    int k = c * 32 + (lane >> 4) * 8 + j;
    float w = W[(size_t)n * K + k];
    unsigned short hi = f2bf(w);
    float res = w - bf2f(hi);
    unsigned short lo = f2bf(res);
    size_t b = (size_t)group * 1024 + (size_t)lane * 16;
    Wf[b + j]     = (short)hi;
    Wf[b + 8 + j] = (short)lo;
}

// one launch preps all six weights; block ranges hardcoded for this problem
__global__ __launch_bounds__(256) void k_wprep_all(
        const float* W1a, short* Q1a, const float* W2a, short* Q2a,
        const float* W1b, short* Q1b, const float* W2b, short* Q2b,
        const float* Wf1, short* Qf1, const float* Wf2, short* Qf2) {
    int b = blockIdx.x;
    const float* W; short* Q; int K, M, lb;
    if      (b < 128)  { W = W1a; Q = Q1a; K = 128; M = 256; lb = b; }
    else if (b < 384)  { W = W2a; Q = Q2a; K = 256; M = 256; lb = b - 128; }
    else if (b < 640)  { W = W1b; Q = Q1b; K = 256; M = 256; lb = b - 384; }
    else if (b < 896)  { W = W2b; Q = Q2b; K = 256; M = 256; lb = b - 640; }
    else if (b < 1152) { W = Wf1; Q = Qf1; K = 256; M = 256; lb = b - 896; }
    else               { W = Wf2; Q = Qf2; K = 256; M = 64;  lb = b - 1152; }
    wprep_body(W, Q, K, M, lb * 256 + threadIdx.x);
}

__device__ inline void split8(float4 a, float4 b, bf8& hi, bf8& lo) {
    float v[8] = {a.x, a.y, a.z, a.w, b.x, b.y, b.z, b.w};
#pragma unroll
    for (int i = 0; i < 8; ++i) {
        unsigned short h = f2bf(v[i]);
        float res = v[i] - bf2f(h);
        hi[i] = (short)h;
        lo[i] = (short)f2bf(res);
    }
}

// ---------------------------------------------------------------------------
// Fused MLP: C = relu(A @ W1^T + b1) @ W2^T + b2    (A: [N,K], hidden 256,
// out MO). Block = 256 thr = 4 waves, tile = 64 rows x all cols.
// ABF: A is bf16 (exact -> lo part zero -> 2 MFMAs/tile, no split VALU).
// OBF: output stored as bf16 (RNE), else fp32.
// Hidden tile round-trips LDS fp32 (stride 260: 16B-aligned, <=2-way banks).
// ---------------------------------------------------------------------------
template <int K, int MO, bool ABF, bool OBF>
__global__ __launch_bounds__(256) void k_mlp(const void* __restrict__ Av,
                                             const short* __restrict__ Wq1,
                                             const float* __restrict__ b1,
                                             const short* __restrict__ Wq2,
                                             const float* __restrict__ b2,
                                             void* __restrict__ Cv, int N) {
    constexpr int MH   = 256;
    constexpr int NCT1 = MH / 64;   // 4 col-tiles per wave (GEMM1)
    constexpr int NCH1 = K / 32;
    constexpr int NCH2 = MH / 32;   // 8
    constexpr int NCT2 = MO / 64;   // 4 or 1
    constexpr int LS   = 260;       // LDS row stride (words)
    __shared__ float Hs[64 * LS];

    const int t    = threadIdx.x;
    const int lane = t & 63;
    const int wq   = t >> 6;
    const int r0   = blockIdx.x * 64;
    const int lm   = lane & 15;
    const int lq   = lane >> 4;

    // ---- GEMM1: A @ W1^T -> acc ----
    f4 acc[4][NCT1];
#pragma unroll
    for (int rt = 0; rt < 4; ++rt)
#pragma unroll
        for (int ct = 0; ct < NCT1; ++ct) acc[rt][ct] = (f4){0.f, 0.f, 0.f, 0.f};

#pragma unroll 2
    for (int c = 0; c < NCH1; ++c) {
        const int kk = c * 32 + lq * 8;
        bf8 ah[4], al[4];
#pragma unroll
        for (int rt = 0; rt < 4; ++rt) {
            int gr = r0 + rt * 16 + lm;
            if (gr >= N) gr = N - 1;             // clamp: valid mem, rows unused
            if constexpr (ABF) {
                const unsigned short* ap = (const unsigned short*)Av + (size_t)gr * K + kk;
                ah[rt] = *(const bf8*)ap;
            } else {
                const float* ap = (const float*)Av + (size_t)gr * K + kk;
                float4 a01 = *(const float4*)(ap + 0);
                float4 a23 = *(const float4*)(ap + 4);
                split8(a01, a23, ah[rt], al[rt]);
            }
        }
#pragma unroll
        for (int ct = 0; ct < NCT1; ++ct) {
            const int ctg = wq * NCT1 + ct;
            const short* wp = Wq1 + ((size_t)(c * (MH / 16) + ctg) * 64 + lane) * 16;
            bf8 wh = *(const bf8*)(wp);
            bf8 wl = *(const bf8*)(wp + 8);
#pragma unroll
            for (int rt = 0; rt < 4; ++rt) {
                acc[rt][ct] = __builtin_amdgcn_mfma_f32_16x16x32_bf16(ah[rt], wh, acc[rt][ct], 0, 0, 0);
                acc[rt][ct] = __builtin_amdgcn_mfma_f32_16x16x32_bf16(ah[rt], wl, acc[rt][ct], 0, 0, 0);
                if constexpr (!ABF)
                    acc[rt][ct] = __builtin_amdgcn_mfma_f32_16x16x32_bf16(al[rt], wh, acc[rt][ct], 0, 0, 0);
            }
        }
    }

    // ---- H = relu(acc + b1) -> LDS (C-layout write) ----
#pragma unroll
    for (int ct = 0; ct < NCT1; ++ct) {
        const int col = wq * 64 + ct * 16 + lm;
        const float bv = b1[col];
#pragma unroll
        for (int rt = 0; rt < 4; ++rt) {
#pragma unroll
            for (int reg = 0; reg < 4; ++reg) {
                int rrow = rt * 16 + lq * 4 + reg;
                float v = acc[rt][ct][reg] + bv;
                v = v > 0.f ? v : 0.f;
                Hs[rrow * LS + col] = v;
            }
        }
    }
    __syncthreads();

    // ---- GEMM2: H @ W2^T + b2 -> C ----
    f4 acc2[4][NCT2];
#pragma unroll
    for (int rt = 0; rt < 4; ++rt)
#pragma unroll
        for (int ct = 0; ct < NCT2; ++ct) acc2[rt][ct] = (f4){0.f, 0.f, 0.f, 0.f};

#pragma unroll 2
    for (int c = 0; c < NCH2; ++c) {
        const int kk = c * 32 + lq * 8;
        bf8 ah[4], al[4];
#pragma unroll
        for (int rt = 0; rt < 4; ++rt) {
            const float* hp = &Hs[(rt * 16 + lm) * LS + kk];
            float4 a01 = *(const float4*)(hp + 0);
            float4 a23 = *(const float4*)(hp + 4);
            split8(a01, a23, ah[rt], al[rt]);
        }
#pragma unroll
        for (int ct = 0; ct < NCT2; ++ct) {
            const int ctg = wq * NCT2 + ct;
            const short* wp = Wq2 + ((size_t)(c * (MO / 16) + ctg) * 64 + lane) * 16;
            bf8 wh = *(const bf8*)(wp);
            bf8 wl = *(const bf8*)(wp + 8);
#pragma unroll
            for (int rt = 0; rt < 4; ++rt) {
                acc2[rt][ct] = __builtin_amdgcn_mfma_f32_16x16x32_bf16(ah[rt], wh, acc2[rt][ct], 0, 0, 0);
                acc2[rt][ct] = __builtin_amdgcn_mfma_f32_16x16x32_bf16(ah[rt], wl, acc2[rt][ct], 0, 0, 0);
                acc2[rt][ct] = __builtin_amdgcn_mfma_f32_16x16x32_bf16(al[rt], wh, acc2[rt][ct], 0, 0, 0);
            }
        }
    }

#pragma unroll
    for (int ct = 0; ct < NCT2; ++ct) {
        const int col = wq * (MO / 4) + ct * 16 + lm;
        const float bv = b2[col];
#pragma unroll
        for (int rt = 0; rt < 4; ++rt) {
#pragma unroll
            for (int reg = 0; reg < 4; ++reg) {
                int n = r0 + rt * 16 + lq * 4 + reg;
                if (n < N) {
                    float v = acc2[rt][ct][reg] + bv;
                    if constexpr (OBF)
                        ((unsigned short*)Cv)[(size_t)n * MO + col] = f2bf(v);
                    else
                        ((float*)Cv)[(size_t)n * MO + col] = v;
                }
            }
        }
    }
}

extern "C" void kernel_launch(void* const* d_in, const int* in_sizes, int n_in,
                              void* d_out, int out_size, void* d_ws, size_t ws_size,
                              hipStream_t stream) {
    const float* x    = (const float*)d_in[0];
    const int*   row  = (const int*)d_in[1];
    const int*   col  = (const int*)d_in[2];
    const float* vals = (const float*)d_in[3];
    const float* eps0 = (const float*)d_in[4];
    const float* W1a  = (const float*)d_in[5];
    const float* b1a  = (const float*)d_in[6];
    const float* W2a  = (const float*)d_in[7];
    const float* b2a  = (const float*)d_in[8];
    const float* eps1 = (const float*)d_in[9];
    const float* W1b  = (const float*)d_in[10];
    const float* b1b  = (const float*)d_in[11];
    const float* W2b  = (const float*)d_in[12];
    const float* b2b  = (const float*)d_in[13];
    const float* Wf1  = (const float*)d_in[14];
    const float* bf1  = (const float*)d_in[15];
    const float* Wf2  = (const float*)d_in[16];
    const float* bf2  = (const float*)d_in[17];
    float* out = (float*)d_out;

    const int N = in_sizes[0] / 128;  // 100000
    const int E = in_sizes[1];        // 1600000

    char* w = (char*)d_ws;
    auto alloc = [&](size_t bytes) -> void* {
        void* p = (void*)w;
        w += (bytes + 255) & ~(size_t)255;
        return p;
    };
    float*          Y      = (float*)alloc((size_t)N * 256 * 4);          // spmm outputs (fp32)
    unsigned short* Hb     = (unsigned short*)alloc((size_t)N * 256 * 2); // bf16 activations
    unsigned short* xb     = (unsigned short*)alloc((size_t)N * 128 * 2); // bf16 input copy
    int*            cnt    = (int*)alloc((size_t)N * 4);
    int*            basep  = (int*)alloc((size_t)(N + 1) * 4);
    int*            cursor = (int*)alloc((size_t)N * 4);
    int*            part   = (int*)alloc(1024);
    int2*           edges  = (int2*)alloc((size_t)E * 8);
    short* Wq1a = (short*)alloc((size_t)128 * 256 * 2 * 2);
    short* Wq2a = (short*)alloc((size_t)256 * 256 * 2 * 2);
    short* Wq1b = (short*)alloc((size_t)256 * 256 * 2 * 2);
    short* Wq2b = (short*)alloc((size_t)256 * 256 * 2 * 2);
    short* Wqf1 = (short*)alloc((size_t)256 * 256 * 2 * 2);
    short* Wqf2 = (short*)alloc((size_t)256 * 64 * 2 * 2);

    // ---- CSR build ----
    k_zero<<<(N + 255) / 256, 256, 0, stream>>>(cnt, N);
    k_hist<<<(E + 255) / 256, 256, 0, stream>>>(row, cnt, E);
    int nb = (N + 1023) / 1024;  // 98
    k_scan1<<<nb, 256, 0, stream>>>(cnt, basep, part, N);
    k_scan2<<<1, 256, 0, stream>>>(part, nb);
    k_scan3<<<(N + 255) / 256, 256, 0, stream>>>(basep, cursor, part, N, E);
    k_scatter<<<(E + 255) / 256, 256, 0, stream>>>(row, col, vals, cursor, edges, E);

    // ---- weight split+swizzle, input bf16 cast ----
    k_wprep_all<<<1216, 256, 0, stream>>>(W1a, Wq1a, W2a, Wq2a, W1b, Wq1b,
                                          W2b, Wq2b, Wf1, Wqf1, Wf2, Wqf2);
    k_cvt<<<(N * 128 / 4 + 255) / 256, 256, 0, stream>>>(x, xb, N * 128);

    const int gemm_grid = (N + 63) / 64;
    const int spmm_grid = (N + 3) / 4;

    // ---- conv A ----
    k_spmm_bf<128><<<spmm_grid, 256, 0, stream>>>(basep, edges, xb, Y, eps0, N);          // Y[N,128] fp32
    k_mlp<128, 256, false, true><<<gemm_grid, 256, 0, stream>>>(Y, Wq1a, b1a, Wq2a, b2a, Hb, N);  // Hb = h1 bf16

    // ---- conv B ----
    k_spmm_bf<256><<<spmm_grid, 256, 0, stream>>>(basep, edges, Hb, Y, eps1, N);          // Y[N,256] fp32
    k_mlp<256, 256, false, true><<<gemm_grid, 256, 0, stream>>>(Y, Wq1b, b1b, Wq2b, b2b, Hb, N);  // Hb = h2 bf16

    // ---- head (bf16 A fast path) ----
    k_mlp<256, 64, true, false><<<gemm_grid, 256, 0, stream>>>(Hb, Wqf1, bf1, Wqf2, bf2, out, N); // [N,64] fp32
}

// Round 5
// 781.404 us; speedup vs baseline: 2.2823x; 1.1769x over previous
//
#include <hip/hip_runtime.h>
#include <cstdint>
#include <cstddef>

// ---------------------------------------------------------------------------
// GIN forward: h = conv(x; eps0, W1a,W2a) -> conv(h; eps1, W1b,W2b) -> MLP head
// SpMM: per-call CSR build + bf16 multi-edge gather SpMM (fp32 accumulate),
//       emitting PRE-SPLIT hi/lo bf16 planes (exact fp32-split, zero split
//       VALU left in the GEMM critical path).
// MLP:  fused Linear->ReLU->Linear, 32-row tiles, hidden tile kept in LDS as
//       bf16 hi/lo planes (33.8 KB -> 4 blocks/CU). Split-bf16 MFMA
//       (Ah*Wh + Ah*Wl + Al*Wh), fp32-grade accuracy.
// ---------------------------------------------------------------------------

using bf8 = __attribute__((ext_vector_type(8))) short;   // 8 bf16 in 4 VGPRs
using us8 = __attribute__((ext_vector_type(8))) unsigned short;
using f4  = __attribute__((ext_vector_type(4))) float;   // mfma acc

__device__ inline unsigned short f2bf(float f) {          // RNE f32 -> bf16 bits
    unsigned int u = __float_as_uint(f);
    return (unsigned short)((u + 0x7FFFu + ((u >> 16) & 1u)) >> 16);
}
__device__ inline float bf2f(unsigned short h) {
    return __uint_as_float(((unsigned int)h) << 16);
}

__global__ __launch_bounds__(256) void k_zero(int* p, int n) {
    int i = blockIdx.x * 256 + threadIdx.x;
    if (i < n) p[i] = 0;
}

__global__ __launch_bounds__(256) void k_hist(const int* __restrict__ row,
                                              int* __restrict__ cnt, int E) {
    int e = blockIdx.x * 256 + threadIdx.x;
    if (e < E) atomicAdd(&cnt[row[e]], 1);
}

// block scans 1024 elements (256 thr x 4); per-element EXCLUSIVE scan within
// block to base, block total to part[b].
__global__ __launch_bounds__(256) void k_scan1(const int* __restrict__ cnt,
                                               int* __restrict__ base,
                                               int* __restrict__ part, int N) {
    __shared__ int sd[256];
    int t = threadIdx.x;
    int i0 = blockIdx.x * 1024 + t * 4;
    int v0 = (i0 + 0 < N) ? cnt[i0 + 0] : 0;
    int v1 = (i0 + 1 < N) ? cnt[i0 + 1] : 0;
    int v2 = (i0 + 2 < N) ? cnt[i0 + 2] : 0;
    int v3 = (i0 + 3 < N) ? cnt[i0 + 3] : 0;
    int ts = v0 + v1 + v2 + v3;
    sd[t] = ts;
    __syncthreads();
    for (int off = 1; off < 256; off <<= 1) {
        int x = (t >= off) ? sd[t - off] : 0;
        __syncthreads();
        sd[t] += x;
        __syncthreads();
    }
    int excl = sd[t] - ts;
    if (i0 + 0 < N) base[i0 + 0] = excl;
    if (i0 + 1 < N) base[i0 + 1] = excl + v0;
    if (i0 + 2 < N) base[i0 + 2] = excl + v0 + v1;
    if (i0 + 3 < N) base[i0 + 3] = excl + v0 + v1 + v2;
    if (t == 255) part[blockIdx.x] = sd[255];
}

__global__ __launch_bounds__(256) void k_scan2(int* part, int NB) {
    __shared__ int sd[256];
    int t = threadIdx.x;
    int v = (t < NB) ? part[t] : 0;
    sd[t] = v;
    __syncthreads();
    for (int off = 1; off < 256; off <<= 1) {
        int x = (t >= off) ? sd[t - off] : 0;
        __syncthreads();
        sd[t] += x;
        __syncthreads();
    }
    if (t < NB) part[t] = sd[t] - v;
}

__global__ __launch_bounds__(256) void k_scan3(int* __restrict__ base,
                                               int* __restrict__ cursor,
                                               const int* __restrict__ part,
                                               int N, int E) {
    int i = blockIdx.x * 256 + threadIdx.x;
    if (i < N) {
        int b = base[i] + part[i >> 10];
        base[i] = b;
        cursor[i] = b;
    }
    if (i == 0) base[N] = E;
}

__global__ __launch_bounds__(256) void k_scatter(const int* __restrict__ row,
                                                 const int* __restrict__ col,
                                                 const float* __restrict__ vals,
                                                 int* __restrict__ cursor,
                                                 int2* __restrict__ edges, int E) {
    int e = blockIdx.x * 256 + threadIdx.x;
    if (e < E) {
        int p = atomicAdd(&cursor[row[e]], 1);
        edges[p] = make_int2(col[e], __float_as_int(vals[e]));
    }
}

// fp32 -> bf16 cast, 4 elems/thread (n divisible by 4)
__global__ __launch_bounds__(256) void k_cvt(const float* __restrict__ x,
                                             unsigned short* __restrict__ xb, int n) {
    int i = (blockIdx.x * 256 + threadIdx.x) * 4;
    if (i < n) {
        float4 v = *(const float4*)(x + i);
        ushort4 o = {f2bf(v.x), f2bf(v.y), f2bf(v.z), f2bf(v.w)};
        *(ushort4*)(xb + i) = o;
    }
}

// ---------------------------------------------------------------------------
// Wave-per-node CSR SpMM on bf16 rows, fp32 accumulate, fused eps-residual:
//   Y[i] = (1+eps)*Xb[i] + sum_e val[e] * Xb[col[e]]
// Output written as SPLIT bf16 planes: Yhi = RNE(Y), Ylo = RNE(Y - Yhi)
// (feeds the MLP's 3-MFMA split path with zero conversion VALU there).
// ---------------------------------------------------------------------------
template <int D>
__global__ __launch_bounds__(256) void k_spmm_bf(const int* __restrict__ base,
                                                 const int2* __restrict__ edges,
                                                 const unsigned short* __restrict__ Xb,
                                                 unsigned short* __restrict__ Yhi,
                                                 unsigned short* __restrict__ Ylo,
                                                 const float* __restrict__ epsp,
                                                 int N) {
    constexpr int L = D / 8;    // lanes per row (16 or 32)
    constexpr int R = 64 / L;   // edges per gather instr (4 or 2)
    constexpr int U = 8 / R;    // instrs per inner iter -> 8 edges/iter
    int node = blockIdx.x * 4 + (threadIdx.x >> 6);
    if (node >= N) return;
    const int lane = threadIdx.x & 63;
    const int sub  = lane % L;   // 8-col group within row
    const int part = lane / L;   // which edge of the group
    const float scale = 1.0f + epsp[0];

    float acc[8];
#pragma unroll
    for (int k = 0; k < 8; ++k) acc[k] = 0.0f;

    const int s = base[node];
    const int e = base[node + 1];
    for (int i0 = s; i0 < e; i0 += 64) {
        int rem = e - i0;
        int idx = i0 + (lane < rem ? lane : 0);
        int2 ed = edges[idx];
        int   ci = ed.x;
        float vi = (lane < rem) ? __int_as_float(ed.y) : 0.0f;
        int lim = rem < 64 ? rem : 64;
        for (int j = 0; j < lim; j += 8) {
            int cc[U]; float vv[U];
#pragma unroll
            for (int u = 0; u < U; ++u) {
                int sl = j + u * R + part;      // <= 63 always
                cc[u] = __shfl(ci, sl);
                vv[u] = __shfl(vi, sl);
            }
            us8 g[U];
#pragma unroll
            for (int u = 0; u < U; ++u)
                g[u] = *(const us8*)(Xb + (size_t)cc[u] * D + sub * 8);
#pragma unroll
            for (int u = 0; u < U; ++u)
#pragma unroll
                for (int k = 0; k < 8; ++k)
                    acc[k] = fmaf(bf2f(g[u][k]), vv[u], acc[k]);
        }
    }

    // butterfly-reduce across edge parts (lanes L, 2L, ... apart)
#pragma unroll
    for (int st = L; st < 64; st <<= 1)
#pragma unroll
        for (int k = 0; k < 8; ++k)
            acc[k] += __shfl_xor(acc[k], st);

    if (part == 0) {
        us8 xs = *(const us8*)(Xb + (size_t)node * D + sub * 8);
        us8 hi8, lo8;
#pragma unroll
        for (int k = 0; k < 8; ++k) {
            float o = acc[k] + scale * bf2f(xs[k]);
            unsigned short h = f2bf(o);
            hi8[k] = h;
            lo8[k] = f2bf(o - bf2f(h));
        }
        *(us8*)(Yhi + (size_t)node * D + sub * 8) = hi8;
        *(us8*)(Ylo + (size_t)node * D + sub * 8) = lo8;
    }
}

// ---------------------------------------------------------------------------
// W prep: split W[M][K] fp32 into bf16 hi/lo in exact B-fragment order for
// mfma_f32_16x16x32_bf16:
//   Wf[((c*(M/16)+ct)*64 + lane)*16 + {0..7}=hi, {8..15}=lo]
// where B[k][n]: n = ct*16 + (lane&15), k = c*32 + (lane>>4)*8 + j.
// ---------------------------------------------------------------------------
__device__ inline void wprep_body(const float* __restrict__ W,
                                  short* __restrict__ Wf, int K, int M, int idx) {
    int group = idx >> 9;          // (c, ct)
    int r     = idx & 511;
    int lane  = r >> 3;
    int j     = r & 7;
    int c  = group / (M / 16);
    int ct = group - c * (M / 16);
    int n = ct * 16 + (lane & 15);
    int k = c * 32 + (lane >> 4) * 8 + j;
    float w = W[(size_t)n * K + k];
    unsigned short hi = f2bf(w);
    float res = w - bf2f(hi);
    unsigned short lo = f2bf(res);
    size_t b = (size_t)group * 1024 + (size_t)lane * 16;
    Wf[b + j]     = (short)hi;
    Wf[b + 8 + j] = (short)lo;
}

// one launch preps all six weights; block ranges hardcoded for this problem
__global__ __launch_bounds__(256) void k_wprep_all(
        const float* W1a, short* Q1a, const float* W2a, short* Q2a,
        const float* W1b, short* Q1b, const float* W2b, short* Q2b,
        const float* Wf1, short* Qf1, const float* Wf2, short* Qf2) {
    int b = blockIdx.x;
    const float* W; short* Q; int K, M, lb;
    if      (b < 128)  { W = W1a; Q = Q1a; K = 128; M = 256; lb = b; }
    else if (b < 384)  { W = W2a; Q = Q2a; K = 256; M = 256; lb = b - 128; }
    else if (b < 640)  { W = W1b; Q = Q1b; K = 256; M = 256; lb = b - 384; }
    else if (b < 896)  { W = W2b; Q = Q2b; K = 256; M = 256; lb = b - 640; }
    else if (b < 1152) { W = Wf1; Q = Qf1; K = 256; M = 256; lb = b - 896; }
    else               { W = Wf2; Q = Qf2; K = 256; M = 64;  lb = b - 1152; }
    wprep_body(W, Q, K, M, lb * 256 + threadIdx.x);
}

// ---------------------------------------------------------------------------
// Fused MLP: C = relu(A @ W1^T + b1) @ W2^T + b2    (A: [N,K], hidden 256,
// out MO). Block = 256 thr = 4 waves; tile = 32 rows x all cols.
// ASPLIT: A given as hi/lo bf16 planes (3 MFMAs/tile); else single bf16
//         plane (exact, 2 MFMAs/tile).
// Hidden tile lives in LDS as bf16 hi/lo planes [32][264] (stride 132 words
// = 4 mod 32 -> ds_read_b128 conflict-free; 33.8 KB -> 4 blocks/CU).
// OBF: output stored bf16 (RNE), else fp32.
// ---------------------------------------------------------------------------
template <int K, int MO, bool ASPLIT, bool OBF>
__global__ __launch_bounds__(256, 4) void k_mlp(const unsigned short* __restrict__ Ahi,
                                                const unsigned short* __restrict__ Alo,
                                                const short* __restrict__ Wq1,
                                                const float* __restrict__ b1,
                                                const short* __restrict__ Wq2,
                                                const float* __restrict__ b2,
                                                void* __restrict__ Cv, int N) {
    constexpr int MH   = 256;
    constexpr int NCT1 = MH / 64;   // 4 col-tiles per wave (GEMM1)
    constexpr int NCH1 = K / 32;
    constexpr int NCH2 = MH / 32;   // 8
    constexpr int NCT2 = MO / 64;   // 4 or 1
    constexpr int HS   = 264;       // LDS row stride in halves (132 words)
    __shared__ unsigned short Hhi[32 * HS];
    __shared__ unsigned short Hlo[32 * HS];

    const int t    = threadIdx.x;
    const int lane = t & 63;
    const int wq   = t >> 6;
    const int r0   = blockIdx.x * 32;
    const int lm   = lane & 15;
    const int lq   = lane >> 4;

    // ---- GEMM1: A @ W1^T -> acc ----
    f4 acc[2][NCT1];
#pragma unroll
    for (int rt = 0; rt < 2; ++rt)
#pragma unroll
        for (int ct = 0; ct < NCT1; ++ct) acc[rt][ct] = (f4){0.f, 0.f, 0.f, 0.f};

#pragma unroll 2
    for (int c = 0; c < NCH1; ++c) {
        const int kk = c * 32 + lq * 8;
        bf8 ah[2], al[2];
#pragma unroll
        for (int rt = 0; rt < 2; ++rt) {
            int gr = r0 + rt * 16 + lm;
            if (gr >= N) gr = N - 1;             // clamp: valid mem, rows unused
            ah[rt] = *(const bf8*)(Ahi + (size_t)gr * K + kk);
            if constexpr (ASPLIT)
                al[rt] = *(const bf8*)(Alo + (size_t)gr * K + kk);
        }
#pragma unroll
        for (int ct = 0; ct < NCT1; ++ct) {
            const int ctg = wq * NCT1 + ct;
            const short* wp = Wq1 + ((size_t)(c * (MH / 16) + ctg) * 64 + lane) * 16;
            bf8 wh = *(const bf8*)(wp);
            bf8 wl = *(const bf8*)(wp + 8);
#pragma unroll
            for (int rt = 0; rt < 2; ++rt) {
                acc[rt][ct] = __builtin_amdgcn_mfma_f32_16x16x32_bf16(ah[rt], wh, acc[rt][ct], 0, 0, 0);
                acc[rt][ct] = __builtin_amdgcn_mfma_f32_16x16x32_bf16(ah[rt], wl, acc[rt][ct], 0, 0, 0);
                if constexpr (ASPLIT)
                    acc[rt][ct] = __builtin_amdgcn_mfma_f32_16x16x32_bf16(al[rt], wh, acc[rt][ct], 0, 0, 0);
            }
        }
    }

    // ---- H = relu(acc + b1), split to bf16 hi/lo -> LDS planes ----
#pragma unroll
    for (int ct = 0; ct < NCT1; ++ct) {
        const int col = wq * 64 + ct * 16 + lm;
        const float bv = b1[col];
#pragma unroll
        for (int rt = 0; rt < 2; ++rt) {
#pragma unroll
            for (int reg = 0; reg < 4; ++reg) {
                int rrow = rt * 16 + lq * 4 + reg;
                float v = acc[rt][ct][reg] + bv;
                v = v > 0.f ? v : 0.f;
                unsigned short h = f2bf(v);
                Hhi[rrow * HS + col] = h;
                Hlo[rrow * HS + col] = f2bf(v - bf2f(h));
            }
        }
    }
    __syncthreads();

    // ---- GEMM2: H @ W2^T + b2 -> C ----
    f4 acc2[2][NCT2];
#pragma unroll
    for (int rt = 0; rt < 2; ++rt)
#pragma unroll
        for (int ct = 0; ct < NCT2; ++ct) acc2[rt][ct] = (f4){0.f, 0.f, 0.f, 0.f};

#pragma unroll 2
    for (int c = 0; c < NCH2; ++c) {
        const int kk = c * 32 + lq * 8;
        bf8 hh[2], hl[2];
#pragma unroll
        for (int rt = 0; rt < 2; ++rt) {
            const int ho = (rt * 16 + lm) * HS + kk;
            hh[rt] = *(const bf8*)(Hhi + ho);
            hl[rt] = *(const bf8*)(Hlo + ho);
        }
#pragma unroll
        for (int ct = 0; ct < NCT2; ++ct) {
            const int ctg = wq * NCT2 + ct;
            const short* wp = Wq2 + ((size_t)(c * (MO / 16) + ctg) * 64 + lane) * 16;
            bf8 wh = *(const bf8*)(wp);
            bf8 wl = *(const bf8*)(wp + 8);
#pragma unroll
            for (int rt = 0; rt < 2; ++rt) {
                acc2[rt][ct] = __builtin_amdgcn_mfma_f32_16x16x32_bf16(hh[rt], wh, acc2[rt][ct], 0, 0, 0);
                acc2[rt][ct] = __builtin_amdgcn_mfma_f32_16x16x32_bf16(hh[rt], wl, acc2[rt][ct], 0, 0, 0);
                acc2[rt][ct] = __builtin_amdgcn_mfma_f32_16x16x32_bf16(hl[rt], wh, acc2[rt][ct], 0, 0, 0);
            }
        }
    }

#pragma unroll
    for (int ct = 0; ct < NCT2; ++ct) {
        const int col = wq * (MO / 4) + ct * 16 + lm;
        const float bv = b2[col];
#pragma unroll
        for (int rt = 0; rt < 2; ++rt) {
#pragma unroll
            for (int reg = 0; reg < 4; ++reg) {
                int n = r0 + rt * 16 + lq * 4 + reg;
                if (n < N) {
                    float v = acc2[rt][ct][reg] + bv;
                    if constexpr (OBF)
                        ((unsigned short*)Cv)[(size_t)n * MO + col] = f2bf(v);
                    else
                        ((float*)Cv)[(size_t)n * MO + col] = v;
                }
            }
        }
    }
}

extern "C" void kernel_launch(void* const* d_in, const int* in_sizes, int n_in,
                              void* d_out, int out_size, void* d_ws, size_t ws_size,
                              hipStream_t stream) {
    const float* x    = (const float*)d_in[0];
    const int*   row  = (const int*)d_in[1];
    const int*   col  = (const int*)d_in[2];
    const float* vals = (const float*)d_in[3];
    const float* eps0 = (const float*)d_in[4];
    const float* W1a  = (const float*)d_in[5];
    const float* b1a  = (const float*)d_in[6];
    const float* W2a  = (const float*)d_in[7];
    const float* b2a  = (const float*)d_in[8];
    const float* eps1 = (const float*)d_in[9];
    const float* W1b  = (const float*)d_in[10];
    const float* b1b  = (const float*)d_in[11];
    const float* W2b  = (const float*)d_in[12];
    const float* b2b  = (const float*)d_in[13];
    const float* Wf1  = (const float*)d_in[14];
    const float* bf1  = (const float*)d_in[15];
    const float* Wf2  = (const float*)d_in[16];
    const float* bf2  = (const float*)d_in[17];
    float* out = (float*)d_out;

    const int N = in_sizes[0] / 128;  // 100000
    const int E = in_sizes[1];        // 1600000

    char* w = (char*)d_ws;
    auto alloc = [&](size_t bytes) -> void* {
        void* p = (void*)w;
        w += (bytes + 255) & ~(size_t)255;
        return p;
    };
    unsigned short* Yhi    = (unsigned short*)alloc((size_t)N * 256 * 2); // spmm out hi
    unsigned short* Ylo    = (unsigned short*)alloc((size_t)N * 256 * 2); // spmm out lo
    unsigned short* Hb     = (unsigned short*)alloc((size_t)N * 256 * 2); // bf16 activations
    unsigned short* xb     = (unsigned short*)alloc((size_t)N * 128 * 2); // bf16 input copy
    int*            cnt    = (int*)alloc((size_t)N * 4);
    int*            basep  = (int*)alloc((size_t)(N + 1) * 4);
    int*            cursor = (int*)alloc((size_t)N * 4);
    int*            part   = (int*)alloc(1024);
    int2*           edges  = (int2*)alloc((size_t)E * 8);
    short* Wq1a = (short*)alloc((size_t)128 * 256 * 2 * 2);
    short* Wq2a = (short*)alloc((size_t)256 * 256 * 2 * 2);
    short* Wq1b = (short*)alloc((size_t)256 * 256 * 2 * 2);
    short* Wq2b = (short*)alloc((size_t)256 * 256 * 2 * 2);
    short* Wqf1 = (short*)alloc((size_t)256 * 256 * 2 * 2);
    short* Wqf2 = (short*)alloc((size_t)256 * 64 * 2 * 2);

    // ---- CSR build ----
    k_zero<<<(N + 255) / 256, 256, 0, stream>>>(cnt, N);
    k_hist<<<(E + 255) / 256, 256, 0, stream>>>(row, cnt, E);
    int nb = (N + 1023) / 1024;  // 98
    k_scan1<<<nb, 256, 0, stream>>>(cnt, basep, part, N);
    k_scan2<<<1, 256, 0, stream>>>(part, nb);
    k_scan3<<<(N + 255) / 256, 256, 0, stream>>>(basep, cursor, part, N, E);
    k_scatter<<<(E + 255) / 256, 256, 0, stream>>>(row, col, vals, cursor, edges, E);

    // ---- weight split+swizzle, input bf16 cast ----
    k_wprep_all<<<1216, 256, 0, stream>>>(W1a, Wq1a, W2a, Wq2a, W1b, Wq1b,
                                          W2b, Wq2b, Wf1, Wqf1, Wf2, Wqf2);
    k_cvt<<<(N * 128 / 4 + 255) / 256, 256, 0, stream>>>(x, xb, N * 128);

    const int mlp_grid  = (N + 31) / 32;
    const int spmm_grid = (N + 3) / 4;

    // ---- conv A ----
    k_spmm_bf<128><<<spmm_grid, 256, 0, stream>>>(basep, edges, xb, Yhi, Ylo, eps0, N);
    k_mlp<128, 256, true, true><<<mlp_grid, 256, 0, stream>>>(Yhi, Ylo, Wq1a, b1a, Wq2a, b2a, Hb, N);

    // ---- conv B ----
    k_spmm_bf<256><<<spmm_grid, 256, 0, stream>>>(basep, edges, Hb, Yhi, Ylo, eps1, N);
    k_mlp<256, 256, true, true><<<mlp_grid, 256, 0, stream>>>(Yhi, Ylo, Wq1b, b1b, Wq2b, b2b, Hb, N);

    // ---- head (single-plane bf16 A, exact -> 2 MFMAs in GEMM1) ----
    k_mlp<256, 64, false, false><<<mlp_grid, 256, 0, stream>>>(Hb, nullptr, Wqf1, bf1, Wqf2, bf2, out, N);
}